// Round 1
// baseline (2158.102 us; speedup 1.0000x reference)
//
#include <hip/hip_runtime.h>
#include <cstdint>
#include <cstddef>

#define BB 8
#define SS 2
#define TT 512
#define CC 2048
#define ND 1024
#define AD 16384
#define NN 256
#define AN 2048
#define NEGV -1e30f

// ---------------------------------------------------------------------------
// prep: per-graph counting sort of arcs by dst (CSR), plus a degree-sorted
// state order so waves get balanced arc counts. One block per graph,
// blockDim.x == N (power of 2).
// ---------------------------------------------------------------------------
__global__ void prep_kernel(const int* __restrict__ src, const int* __restrict__ dst,
                            const int* __restrict__ pdf, const float* __restrict__ w,
                            uint2* __restrict__ arcs, unsigned* __restrict__ rowptr,
                            unsigned* __restrict__ order, int N, int A)
{
    __shared__ int cnt[1024];
    __shared__ int pos[1024];
    __shared__ int h2[64];
    const int g = blockIdx.x;
    src += (size_t)g * A; dst += (size_t)g * A; pdf += (size_t)g * A; w += (size_t)g * A;
    arcs += (size_t)g * A; rowptr += (size_t)g * (N + 1); order += (size_t)g * N;
    const int tid = threadIdx.x;
    cnt[tid] = 0;
    if (tid < 64) h2[tid] = 0;
    __syncthreads();
    for (int a = tid; a < A; a += blockDim.x) atomicAdd(&cnt[dst[a]], 1);
    __syncthreads();
    const int deg = cnt[tid];
    // inclusive scan of cnt into pos (Hillis-Steele)
    pos[tid] = deg;
    __syncthreads();
    for (int off = 1; off < blockDim.x; off <<= 1) {
        int add = (tid >= off) ? pos[tid - off] : 0;
        __syncthreads();
        pos[tid] += add;
        __syncthreads();
    }
    const int excl = pos[tid] - deg;
    rowptr[tid] = (unsigned)excl;
    if (tid == blockDim.x - 1) rowptr[N] = (unsigned)A;
    // degree-balanced lane assignment: states sorted ascending by in-degree
    const int db = deg > 63 ? 63 : deg;
    atomicAdd(&h2[db], 1);
    __syncthreads();
    if (tid == 0) {
        int run = 0;
        for (int d2 = 0; d2 < 64; ++d2) { int c2 = h2[d2]; h2[d2] = run; run += c2; }
    }
    __syncthreads();
    const int rank = atomicAdd(&h2[db], 1);
    order[rank] = (unsigned)tid;
    // scatter arcs grouped by dst; record = {src | pdf<<16, weight bits}
    cnt[tid] = excl;
    __syncthreads();
    for (int a = tid; a < A; a += blockDim.x) {
        const int d2 = dst[a];
        const int p2 = atomicAdd(&cnt[d2], 1);
        arcs[p2] = make_uint2((unsigned)src[a] | ((unsigned)pdf[a] << 16),
                              __float_as_uint(w[a]));
    }
}

// ---------------------------------------------------------------------------
// FSM forward: thread tid owns state j = order[tid] (tid < N). alpha in LDS,
// llh row double-buffered in LDS, arcs staged in LDS. Online logsumexp per
// state per step (single exp per arc), reference semantics replicated:
//   mc = max(m, NEG); s' = s * exp(m - mc); new = mc + log(max(s', 1e-30))
// ---------------------------------------------------------------------------
__device__ void fsm_forward(int N, int A,
    const float* __restrict__ rowbase, int L,
    const uint2* __restrict__ arcs_g, const unsigned* __restrict__ rowptr,
    const unsigned* __restrict__ order,
    const float* __restrict__ initv, const float* __restrict__ finalv,
    float* __restrict__ res,
    float* llh0, float* llh1, float* alpha_s, uint2* arcs_s)
{
    const int tid = threadIdx.x;
    // stage arc list into LDS (coalesced, one-time)
    for (int a = tid; a < A; a += 1024) arcs_s[a] = arcs_g[a];
    const bool st = tid < N;
    int j = 0; unsigned r0 = 0, r1 = 0; float fin = 0.f;
    if (st) {
        j = (int)order[tid];
        alpha_s[j] = initv[j];
        r0 = rowptr[j]; r1 = rowptr[j + 1];
        fin = finalv[j];
    }
    // preload llh row 0 (L >= 1 always here; guard anyway)
    if (L > 0) {
        llh0[tid]        = rowbase[tid];
        llh0[tid + 1024] = rowbase[tid + 1024];
    }
    __syncthreads();
    for (int t = 0; t < L; ++t) {
        float* cur = (t & 1) ? llh1 : llh0;
        float* nxt = (t & 1) ? llh0 : llh1;
        const bool pre = (t + 1 < L);
        float p0 = 0.f, p1 = 0.f;
        if (pre) {
            const float* nb = rowbase + (size_t)(t + 1) * CC;
            p0 = nb[tid];
            p1 = nb[tid + 1024];
        }
        float m = -INFINITY, ss = 0.f;
        for (unsigned k = r0; k < r1; ++k) {
            const uint2 arc = arcs_s[k];
            const int sidx = (int)(arc.x & 0xffffu);
            const int pidx = (int)(arc.x >> 16);
            const float sc = alpha_s[sidx] + __uint_as_float(arc.y) + cur[pidx];
            const float d = sc - m;                 // first iter: +inf
            const float e = __expf(-fabsf(d));      // exp(-inf) = 0
            if (d > 0.f) { ss = ss * e + 1.f; m = sc; }
            else         { ss += e; }
        }
        __syncthreads();
        if (st) {
            const float mc  = fmaxf(m, NEGV);
            const float scs = ss * __expf(m - mc);  // m=-inf (no arcs) -> 0
            alpha_s[j] = mc + __logf(fmaxf(scs, 1e-30f));
        }
        if (pre) { nxt[tid] = p0; nxt[tid + 1024] = p1; }
        __syncthreads();
    }
    // logsumexp(alpha + final) over N states, block-wide tree reduce
    const float v = st ? (alpha_s[j] + fin) : -INFINITY;
    float* red = llh0;   // free now
    red[tid] = v;
    __syncthreads();
    for (int off = 512; off > 0; off >>= 1) {
        if (tid < off) red[tid] = fmaxf(red[tid], red[tid + off]);
        __syncthreads();
    }
    const float M = red[0];
    __syncthreads();
    red[tid] = __expf(v - M);   // v=-inf lanes contribute 0
    __syncthreads();
    for (int off = 512; off > 0; off >>= 1) {
        if (tid < off) red[tid] += red[tid + off];
        __syncthreads();
    }
    if (tid == 0) *res = M + __logf(red[0]);
}

__global__ __launch_bounds__(1024) void fwd_kernel(
    const float* __restrict__ est, const int* __restrict__ seqlen,
    const uint2* __restrict__ den_arcs, const unsigned* __restrict__ den_rowptr,
    const unsigned* __restrict__ den_order,
    const float* __restrict__ den_init, const float* __restrict__ den_final,
    const uint2* __restrict__ num_arcs, const unsigned* __restrict__ num_rowptr,
    const unsigned* __restrict__ num_order,
    const float* __restrict__ num_init, const float* __restrict__ num_final,
    float* __restrict__ res)
{
    extern __shared__ char smem[];
    float* llh0  = (float*)smem;            // 2048 f32
    float* llh1  = llh0 + 2048;             // 2048 f32
    float* alpha = llh1 + 2048;             // 1024 f32
    uint2* arcs_s = (uint2*)(alpha + 1024); // up to 16384 uint2
    const int bid = blockIdx.x;
    if (bid < 16) {
        // denominator: fsm index = s*8 + b, shared graph, llh row of (b, s)
        const int s = bid >> 3, b = bid & 7;
        const float* rowbase = est + (size_t)(b * SS + s) * TT * CC;
        const int L = seqlen[b * SS + s];
        fsm_forward(ND, AD, rowbase, L, den_arcs, den_rowptr, den_order,
                    den_init, den_final, &res[bid], llh0, llh1, alpha, arcs_s);
    } else {
        // numerator: q = p*16 + (s*8 + b); perm p in {0,1}; speaker used = p ? 1-s : s
        const int q = bid - 16;
        const int p = q >> 4, g = q & 15;
        const int s = g >> 3, b = g & 7;
        const int sp = p ? (1 - s) : s;
        const float* rowbase = est + (size_t)(b * SS + sp) * TT * CC;
        const int L = seqlen[b * SS + sp];
        fsm_forward(NN, AN, rowbase, L,
                    num_arcs + (size_t)g * AN,
                    num_rowptr + (size_t)g * (NN + 1),
                    num_order + (size_t)g * NN,
                    num_init + (size_t)g * NN, num_final + (size_t)g * NN,
                    &res[16 + p * 16 + g], llh0, llh1, alpha, arcs_s);
    }
}

// res layout: [0..15] den (s*8+b), [16..31] num perm0, [32..47] num perm1
__global__ void finalize_kernel(const float* __restrict__ res, float* __restrict__ out)
{
    if (threadIdx.x == 0 && blockIdx.x == 0) {
        float loss = 0.f;
        for (int b = 0; b < BB; ++b) {
            const float den = res[b] + res[8 + b];
            const float n0  = res[16 + b] + res[16 + 8 + b];
            const float n1  = res[32 + b] + res[32 + 8 + b];
            const float nm  = fminf(n0, n1);
            loss += -(nm - den);
        }
        out[0] = loss;
    }
}

extern "C" void kernel_launch(void* const* d_in, const int* in_sizes, int n_in,
                              void* d_out, int out_size, void* d_ws, size_t ws_size,
                              hipStream_t stream)
{
    const float* est       = (const float*)d_in[0];
    const int*   seqlen    = (const int*)  d_in[1];
    const int*   den_src   = (const int*)  d_in[2];
    const int*   den_dst   = (const int*)  d_in[3];
    const int*   den_pdf   = (const int*)  d_in[4];
    const float* den_w     = (const float*)d_in[5];
    const float* den_init  = (const float*)d_in[6];
    const float* den_final = (const float*)d_in[7];
    const int*   num_src   = (const int*)  d_in[8];
    const int*   num_dst   = (const int*)  d_in[9];
    const int*   num_pdf   = (const int*)  d_in[10];
    const float* num_w     = (const float*)d_in[11];
    const float* num_init  = (const float*)d_in[12];
    const float* num_final = (const float*)d_in[13];

    char* ws = (char*)d_ws;
    uint2*    den_arcs   = (uint2*)   (ws + 0);        // 131072 B
    uint2*    num_arcs   = (uint2*)   (ws + 131072);   // 262144 B -> end 393216
    unsigned* den_rowptr = (unsigned*)(ws + 393216);   // 4100 B   -> pad to 397568
    unsigned* num_rowptr = (unsigned*)(ws + 397568);   // 16448 B  -> pad to 414208
    unsigned* den_order  = (unsigned*)(ws + 414208);   // 4096 B   -> 418304
    unsigned* num_order  = (unsigned*)(ws + 418304);   // 16384 B  -> 434688
    float*    res        = (float*)   (ws + 434688);   // 192 B

    prep_kernel<<<1, 1024, 0, stream>>>(den_src, den_dst, den_pdf, den_w,
                                        den_arcs, den_rowptr, den_order, ND, AD);
    prep_kernel<<<16, 256, 0, stream>>>(num_src, num_dst, num_pdf, num_w,
                                        num_arcs, num_rowptr, num_order, NN, AN);

    const int shmem = (2048 * 2 + 1024) * (int)sizeof(float) + AD * (int)sizeof(uint2); // 151552
    static bool attr_set = false;
    (void)attr_set;
    hipFuncSetAttribute(reinterpret_cast<const void*>(fwd_kernel),
                        hipFuncAttributeMaxDynamicSharedMemorySize, shmem);

    fwd_kernel<<<48, 1024, shmem, stream>>>(est, seqlen,
                                            den_arcs, den_rowptr, den_order,
                                            den_init, den_final,
                                            num_arcs, num_rowptr, num_order,
                                            num_init, num_final, res);

    finalize_kernel<<<1, 64, 0, stream>>>(res, (float*)d_out);
}